// Round 9
// baseline (62.430 us; speedup 1.0000x reference)
//
#include <hip/hip_runtime.h>
#include <math.h>

#define BB 64
#define NN 8732
#define NV4 (NN / 4)  // 2183
#define CC 21
#define TB 128        // boxes per tile (2 waves)
#define TPB 5         // tiles per block (pipeline depth)
#define NT 69         // tiles per row = ceil(8732/128)
#define GXB 14        // blocks per row = ceil(69/5)

// Monotonic float->uint mapping (total order)
static __device__ __forceinline__ unsigned f2u(float f) {
  unsigned u = __float_as_uint(f);
  return (u & 0x80000000u) ? ~u : (u | 0x80000000u);
}

// Kernel 1: pipelined persistent-tile map. R2-R8's 39-67us plateau was the
// one-shot block structure: every block = load -> barrier -> compute, ~17
// serial generations/CU each paying full exposed memory latency. This
// version: 5 tiles/block, loads for tile t+2 issued while computing tile t
// (sched_barrier(0) fences the scheduler from sinking them), tile t+1
// staged regs->LDS late (T14), raw s_barrier (no vmcnt(0) drain) keeps the
// prefetch in flight across barriers. Latency paid once per block.
__global__ __launch_bounds__(128) void k1_map(
    const float* __restrict__ abd, const float* __restrict__ lbl,
    const float* __restrict__ pbd, const float* __restrict__ plog,
    unsigned* __restrict__ keys, float* __restrict__ cep,
    float* __restrict__ pl, float* __restrict__ pc, int* __restrict__ pcnt) {
  __shared__ __align__(16) float s_plog[2][TB * CC];  // 2 x 10752 B
  __shared__ int s_cls[2][TB];
  __shared__ float s_l[2], s_p[2];
  __shared__ int s_c[2];

  const int b = blockIdx.y;
  const int bx = blockIdx.x;  // 0..13
  const int tid = threadIdx.x;
  const int lane = tid & 63, wv = tid >> 6;
  const size_t rowbase = (size_t)b * NN;
  const float4* plog4 = reinterpret_cast<const float4*>(plog + rowbase * CC);
  const float4* lbl4 = reinterpret_cast<const float4*>(lbl + rowbase * CC);
  const float4* abd4 = reinterpret_cast<const float4*>(abd);
  const float4* pbd4 = reinterpret_cast<const float4*>(pbd);

  float4 Lp[2][6], Ll[2][6], Ab[2], Pb[2];  // 2-deep prefetch reg sets
  float th_loc = 0.f, th_conf = 0.f;
  int th_cnt = 0;

  // Issue all 14 loads of tile tt into reg set s (clamped; always in-bounds).
  auto LOADT = [&](int s, int tt) {
    const int ttc = (tt > NT - 1) ? (NT - 1) : tt;
    const int nbox = min(TB, NN - ttc * TB);
    const int nf4 = (nbox * CC) >> 2;
    const int base4 = ttc * ((TB * CC) >> 2);
#pragma unroll
    for (int it = 0; it < 6; ++it) {
      int t4 = it * TB + tid;
      t4 = (t4 < nf4) ? t4 : (nf4 - 1);
      Lp[s][it] = plog4[base4 + t4];
      Ll[s][it] = lbl4[base4 + t4];
    }
    const int n = ttc * TB + ((tid < nbox) ? tid : (nbox - 1));
    Ab[s] = abd4[rowbase + n];
    Pb[s] = pbd4[rowbase + n];
  };

  // Stage reg set s into LDS buffer u (ds_writes; vmcnt waits are counted
  // by the compiler per-use; these regs were loaded one iteration ago).
  auto STAGE = [&](int s, int u, int tt) {
    const int nbox = min(TB, NN - tt * TB);
    const int nf4 = (nbox * CC) >> 2;
#pragma unroll
    for (int it = 0; it < 6; ++it) {
      const int t4 = it * TB + tid;
      if (t4 < nf4) {
        reinterpret_cast<float4*>(s_plog[u])[t4] = Lp[s][it];
        const float4 v = Ll[s][it];
        const int f0 = t4 * 4;
        int box = f0 / CC;  // magic-mul
        int rem = f0 - box * CC;
        if (v.x != 0.f) s_cls[u][box] = rem;
        if (++rem == CC) { rem = 0; ++box; }
        if (v.y != 0.f) s_cls[u][box] = rem;
        if (++rem == CC) { rem = 0; ++box; }
        if (v.z != 0.f) s_cls[u][box] = rem;
        if (++rem == CC) { rem = 0; ++box; }
        if (v.w != 0.f) s_cls[u][box] = rem;
      }
    }
  };

  auto COMPUTE = [&](int s, int u, int tt) {
    const int nbox = min(TB, NN - tt * TB);
    if (tid >= nbox) return;
    const size_t idx = rowbase + tt * TB + tid;
    const float4 a = Ab[s], p = Pb[s];
    const int isPos = (a.x != 0.f) || (a.y != 0.f) || (a.z != 0.f) || (a.w != 0.f);
    const int cls = s_cls[u][tid];
    float pv[CC];
    float m = -INFINITY, ssum = 0.f, tdot = 0.f;
#pragma unroll
    for (int j = 0; j < CC; ++j) {
      const float v = s_plog[u][tid * CC + j];
      pv[j] = v;
      m = fmaxf(m, v);
      ssum += v;
      tdot = (j == cls) ? v : tdot;  // select, not runtime index (rule #20)
    }
    float es = 0.f;
#pragma unroll
    for (int j = 0; j < CC; ++j) es += expf(pv[j] - m);
    const float pt = tdot / ssum;
    const float ptc = fminf(fmaxf(pt, 1e-7f), 1.0f - 1e-7f);
    const float cp = -logf(ptc);
    const float cel = (m + logf(es)) - tdot;  // mining key (CE from logits)
    keys[idx] = isPos ? 0u : f2u(cel);
    cep[idx] = cp;
    const float dx = p.x - a.x, dy = p.y - a.y, dz = p.z - a.z, dw = p.w - a.w;
    const float axv = fabsf(dx), ayv = fabsf(dy), azv = fabsf(dz), awv = fabsf(dw);
    const float h = (axv <= 1.f ? 0.5f * dx * dx : axv - 0.5f)
                  + (ayv <= 1.f ? 0.5f * dy * dy : ayv - 0.5f)
                  + (azv <= 1.f ? 0.5f * dz * dz : azv - 0.5f)
                  + (awv <= 1.f ? 0.5f * dw * dw : awv - 0.5f);
    if (isPos) {
      th_loc += h * 0.25f;
      th_conf += cp;
      th_cnt += 1;
    }
  };

  // ---- prologue: tiles 0 and 1 of this block are always valid ----
  LOADT(0, bx * TPB + 0);
  LOADT(1, bx * TPB + 1);
  __builtin_amdgcn_sched_barrier(0);
  STAGE(0, 0, bx * TPB + 0);  // exposed latency paid once per block
  asm volatile("s_waitcnt lgkmcnt(0)" ::: "memory");
  __builtin_amdgcn_sched_barrier(0);
  __builtin_amdgcn_s_barrier();
  __builtin_amdgcn_sched_barrier(0);

#pragma unroll
  for (int t = 0; t < TPB; ++t) {
    if (t + 2 < TPB) LOADT(t & 1, bx * TPB + t + 2);  // prefetch 2 ahead
    __builtin_amdgcn_sched_barrier(0);
    const int tt = bx * TPB + t;
    if (tt < NT) COMPUTE(t & 1, t & 1, tt);  // uniform guard
    if (t + 1 < TPB) {
      const int tn = tt + 1;
      if (tn < NT) STAGE((t + 1) & 1, (t + 1) & 1, tn);  // uniform guard
      asm volatile("s_waitcnt lgkmcnt(0)" ::: "memory");
      __builtin_amdgcn_sched_barrier(0);
      __builtin_amdgcn_s_barrier();  // raw: no vmcnt(0) drain, prefetch flies
      __builtin_amdgcn_sched_barrier(0);
    }
  }

  // ---- block reduce of per-thread partials ----
  float lvv = th_loc, pcf = th_conf;
  int pctr = th_cnt;
  for (int off = 32; off > 0; off >>= 1) {
    lvv += __shfl_down(lvv, off, 64);
    pcf += __shfl_down(pcf, off, 64);
    pctr += __shfl_down(pctr, off, 64);
  }
  if (lane == 0) { s_l[wv] = lvv; s_p[wv] = pcf; s_c[wv] = pctr; }
  __syncthreads();
  if (tid == 0) {
    const int bi = b * GXB + bx;
    pl[bi] = s_l[0] + s_l[1];
    pc[bi] = s_p[0] + s_p[1];
    pcnt[bi] = s_c[0] + s_c[1];
  }
}

// Kernel 2: per-row partial-reduce + exact radix-select (unchanged core).
#define K2T 1024
#define K2W 16
#define GX GXB

__global__ __launch_bounds__(K2T) void k2_select(
    const unsigned* __restrict__ keys, const float* __restrict__ cep,
    const float* __restrict__ pl, const float* __restrict__ pc,
    const int* __restrict__ pcnt,
    double* __restrict__ row_loc, double* __restrict__ row_conf,
    int* __restrict__ row_pos) {
  __shared__ unsigned hist[2048];
  __shared__ unsigned wsum[K2W];
  __shared__ unsigned bc[2];
  __shared__ unsigned wtot[K2W];
  __shared__ double s_d[K2W];
  __shared__ double s_rl, s_rc;
  __shared__ int s_pos;
  const int b = blockIdx.x;
  const int tid = threadIdx.x;
  const int lane = tid & 63, wv = tid >> 6;

  if (wv == 0) {
    float a = 0.f, c = 0.f;
    int p = 0;
    for (int i = lane; i < GX; i += 64) {
      a += pl[b * GX + i];
      c += pc[b * GX + i];
      p += pcnt[b * GX + i];
    }
    for (int off = 32; off > 0; off >>= 1) {
      a += __shfl_down(a, off, 64);
      c += __shfl_down(c, off, 64);
      p += __shfl_down(p, off, 64);
    }
    if (lane == 0) { s_rl = (double)a; s_rc = (double)c; s_pos = p; }
  }
  __syncthreads();
  const int pos = s_pos;
  unsigned k = (unsigned)(pos * 3);
  const unsigned negs = (unsigned)(NN - pos);
  if (k > negs) k = negs;

  double neg_total = 0.0;
  if (k > 0) {  // block-uniform branch
    const unsigned* rk = keys + (size_t)b * NN;
    const uint4* rk4 = reinterpret_cast<const uint4*>(rk);
    unsigned want = k;
    unsigned prefix = 0;
    for (int pass = 0; pass < 3; ++pass) {
      const int nb = (pass == 2) ? 1024 : 2048;
      const int shift = (pass == 0) ? 21 : (pass == 1) ? 10 : 0;
      for (int i = tid; i < nb; i += K2T) hist[i] = 0;
      __syncthreads();
      if (pass == 0) {
        for (int t = tid; t < NV4; t += K2T) {
          uint4 v = rk4[t];
          atomicAdd(&hist[v.x >> 21], 1u);
          atomicAdd(&hist[v.y >> 21], 1u);
          atomicAdd(&hist[v.z >> 21], 1u);
          atomicAdd(&hist[v.w >> 21], 1u);
        }
      } else {
        const unsigned pshift = (pass == 1) ? 21u : 10u;
        const unsigned msk = (unsigned)(nb - 1);
        for (int t = tid; t < NV4; t += K2T) {
          uint4 v = rk4[t];
          if ((v.x >> pshift) == prefix) atomicAdd(&hist[(v.x >> shift) & msk], 1u);
          if ((v.y >> pshift) == prefix) atomicAdd(&hist[(v.y >> shift) & msk], 1u);
          if ((v.z >> pshift) == prefix) atomicAdd(&hist[(v.z >> shift) & msk], 1u);
          if ((v.w >> pshift) == prefix) atomicAdd(&hist[(v.w >> shift) & msk], 1u);
        }
      }
      __syncthreads();
      const int PR = nb / K2T;
      unsigned v0, v1 = 0, ls;
      if (PR == 2) {
        v0 = hist[nb - 1 - (tid * 2)];
        v1 = hist[nb - 1 - (tid * 2 + 1)];
        ls = v0 + v1;
      } else {
        v0 = hist[nb - 1 - tid];
        ls = v0;
      }
      unsigned x = ls;
#pragma unroll
      for (int off = 1; off < 64; off <<= 1) {
        unsigned y = __shfl_up(x, off, 64);
        if (lane >= off) x += y;
      }
      if (lane == 63) wsum[wv] = x;
      __syncthreads();
      if (wv == 0 && lane < K2W) {
        unsigned wx = wsum[lane];
#pragma unroll
        for (int off = 1; off < K2W; off <<= 1) {
          unsigned wy = __shfl_up(wx, off, K2W);
          if ((lane & (K2W - 1)) >= off) wx += wy;
        }
        wsum[lane] = wx;
      }
      __syncthreads();
      const unsigned woff = (wv == 0) ? 0u : wsum[wv - 1];
      const unsigned pinc = woff + x;
      if (PR == 2) {
        const unsigned p0 = pinc - ls + v0;
        const unsigned p1 = pinc;
        if (v0 > 0 && p0 >= want && p0 - v0 < want) { bc[0] = (unsigned)(nb - 1 - tid * 2); bc[1] = want - (p0 - v0); }
        if (v1 > 0 && p1 >= want && p1 - v1 < want) { bc[0] = (unsigned)(nb - 1 - (tid * 2 + 1)); bc[1] = want - (p1 - v1); }
      } else {
        if (v0 > 0 && pinc >= want && pinc - v0 < want) { bc[0] = (unsigned)(nb - 1 - tid); bc[1] = want - (pinc - v0); }
      }
      __syncthreads();
      const unsigned d = bc[0];
      want = bc[1];
      prefix = (pass == 0) ? d : ((prefix << ((pass == 1) ? 11 : 10)) | d);
      __syncthreads();
    }
    const unsigned tau = prefix;
    const unsigned neq = want;

    const float* rc = cep + (size_t)b * NN;
    double mysum = 0.0;
    unsigned bbase = 0;
    for (int start = 0; start < NN; start += K2T) {
      const int i = start + tid;
      const unsigned key = (i < NN) ? rk[i] : 0u;
      const bool gt = (i < NN) && (key > tau);
      const bool eq = (i < NN) && (key == tau);
      if (gt) mysum += (double)rc[i];
      const unsigned long long mb = __ballot(eq);
      if (lane == 0) wtot[wv] = (unsigned)__popcll(mb);
      __syncthreads();
      unsigned wpref = 0, tot = 0;
#pragma unroll
      for (int w = 0; w < K2W; ++w) {
        const unsigned c = wtot[w];
        wpref += (w < wv) ? c : 0u;
        tot += c;
      }
      if (eq) {
        const unsigned lanepref = (unsigned)__popcll(mb & ((1ull << lane) - 1ull));
        if (bbase + wpref + lanepref < neq) mysum += (double)rc[i];
      }
      bbase += tot;
      __syncthreads();
    }
    for (int off = 32; off > 0; off >>= 1) mysum += __shfl_down(mysum, off, 64);
    if (lane == 0) s_d[wv] = mysum;
    __syncthreads();
    if (tid == 0) {
#pragma unroll
      for (int w = 0; w < K2W; ++w) neg_total += s_d[w];
    }
  }
  if (tid == 0) {
    row_loc[b] = s_rl;
    row_conf[b] = s_rc + neg_total;
    row_pos[b] = pos;
  }
}

// Kernel 3: reduce 64 rows, finalize the two scalars.
__global__ void k3_final(const double* __restrict__ row_loc,
                         const double* __restrict__ row_conf,
                         const int* __restrict__ row_pos,
                         float* __restrict__ out) {
  const int lane = threadIdx.x;  // 64 threads
  double l = row_loc[lane], c = row_conf[lane];
  int p = row_pos[lane];
  for (int off = 32; off > 0; off >>= 1) {
    l += __shfl_down(l, off, 64);
    c += __shfl_down(c, off, 64);
    p += __shfl_down(p, off, 64);
  }
  if (lane == 0) {
    const double tot = (p > 0) ? (double)p : 1.0;
    out[0] = (float)(l / tot);
    out[1] = (float)(c / tot);
  }
}

extern "C" void kernel_launch(void* const* d_in, const int* in_sizes, int n_in,
                              void* d_out, int out_size, void* d_ws, size_t ws_size,
                              hipStream_t stream) {
  const float* abd = (const float*)d_in[0];
  const float* lbl = (const float*)d_in[1];
  const float* pbd = (const float*)d_in[2];
  const float* plog = (const float*)d_in[3];

  char* ws = (char*)d_ws;
  float* pl = (float*)(ws + 0);              // [BB*GXB] = 896
  float* pc = (float*)(ws + 8960);           // [896]
  int* pcnt = (int*)(ws + 17920);            // [896]
  double* row_loc = (double*)(ws + 26880);   // [64]
  double* row_conf = (double*)(ws + 27392);  // [64]
  int* row_pos = (int*)(ws + 27904);         // [64]
  unsigned* keys = (unsigned*)(ws + 28160);  // [B*N], 16B-aligned
  float* cep = (float*)(ws + 28160 + (size_t)BB * NN * sizeof(unsigned));

  // All scratch is written unconditionally before being read -> no memset.
  dim3 g1(GXB, BB);
  k1_map<<<g1, TB, 0, stream>>>(abd, lbl, pbd, plog, keys, cep, pl, pc, pcnt);
  k2_select<<<BB, K2T, 0, stream>>>(keys, cep, pl, pc, pcnt, row_loc, row_conf, row_pos);
  k3_final<<<1, 64, 0, stream>>>(row_loc, row_conf, row_pos, (float*)d_out);
}

// Round 10
// 42.562 us; speedup vs baseline: 1.4668x; 1.4668x over previous
//
#include <hip/hip_runtime.h>
#include <math.h>

#define BB 64
#define NN 8732
#define NV4 (NN / 4)  // 2183
#define CC 21
#define TB 64         // boxes per block = 1 wave
#define GX 137        // blocks per row = ceil(8732/64)

typedef unsigned int u32;
typedef __attribute__((address_space(1))) const u32 gu32;
typedef __attribute__((address_space(3))) u32 lu32;

// Monotonic float->uint mapping (total order)
static __device__ __forceinline__ unsigned f2u(float f) {
  unsigned u = __float_as_uint(f);
  return (u & 0x80000000u) ? ~u : (u | 0x80000000u);
}

#define GLDS(src, dstbase) \
  __builtin_amdgcn_global_load_lds((gu32*)(const u32*)(src), (lu32*)(u32*)(dstbase), 16, 0, 0)

// Kernel 1: per-box map, ALL input streams via global_load_lds DMA.
// R2-R9 lesson: register-destination loads get SUNK by hipcc to their use
// sites (VGPR=36 tell; asm pins legally sunk too) -> each wave holds 1-2
// outstanding loads -> serialized latency ladders -> 39-44us plateau.
// global_load_lds has NO register destination: it cannot be sunk. All 14
// DMAs issue back-to-back; one vmcnt(0); compute reads LDS. Single-wave
// blocks: no inter-wave convoy, barrier is wave-private.
__global__ __launch_bounds__(64) void k1_map(
    const float* __restrict__ abd, const float* __restrict__ lbl,
    const float* __restrict__ pbd, const float* __restrict__ plog,
    unsigned* __restrict__ keys, float* __restrict__ cep,
    float* __restrict__ pl, float* __restrict__ pc, int* __restrict__ pcnt) {
  __shared__ __align__(16) float s_plog[TB * CC];  // 5376 B
  __shared__ __align__(16) float s_lbl[TB * CC];   // 5376 B
  __shared__ __align__(16) float4 s_ab[TB];        // 1024 B
  __shared__ __align__(16) float4 s_pb[TB];        // 1024 B

  const int b = blockIdx.y;
  const int base = blockIdx.x * TB;
  const int nbox = min(TB, NN - base);
  const int nf4 = (nbox * CC) >> 2;  // 336 full / 147 tail (both exact)
  const int tid = threadIdx.x;
  const size_t rowbase = (size_t)b * NN;

  // ---- stage ALL four streams via un-sinkable DMA ----
  const float4* plog4 = reinterpret_cast<const float4*>(plog + (rowbase + base) * CC);
  const float4* lbl4 = reinterpret_cast<const float4*>(lbl + (rowbase + base) * CC);
#pragma unroll
  for (int it = 0; it < 6; ++it) {
    const int t = it * TB + tid;
    if (t < nf4) {  // dest base wave-uniform; HW adds lane*16 (m104)
      GLDS(plog4 + t, (char*)s_plog + (size_t)it * TB * 16);
      GLDS(lbl4 + t, (char*)s_lbl + (size_t)it * TB * 16);
    }
  }
  if (tid < nbox) {
    GLDS(reinterpret_cast<const float4*>(abd) + rowbase + base + tid, (char*)s_ab);
    GLDS(reinterpret_cast<const float4*>(pbd) + rowbase + base + tid, (char*)s_pb);
  }
  asm volatile("s_waitcnt vmcnt(0)" ::: "memory");
  __builtin_amdgcn_sched_barrier(0);
  __syncthreads();  // single-wave: near-free; guarantees LDS visibility

  float loc = 0.f, pconf = 0.f;
  int isPos = 0;
  if (tid < nbox) {
    const size_t idx = rowbase + base + tid;
    const float4 a = s_ab[tid];
    const float4 p = s_pb[tid];
    isPos = (a.x != 0.f) || (a.y != 0.f) || (a.z != 0.f) || (a.w != 0.f);

    // one-hot class from staged lbl row: static-unrolled scan, no scatter
    int cls = 0;
#pragma unroll
    for (int j = 0; j < CC; ++j)
      cls = (s_lbl[tid * CC + j] != 0.f) ? j : cls;

    float pv[CC];
    float m = -INFINITY, ssum = 0.f, tdot = 0.f;
#pragma unroll
    for (int j = 0; j < CC; ++j) {
      const float v = s_plog[tid * CC + j];
      pv[j] = v;
      m = fmaxf(m, v);
      ssum += v;
      tdot = (j == cls) ? v : tdot;  // select, not runtime index (rule #20)
    }
    float es = 0.f;
#pragma unroll
    for (int j = 0; j < CC; ++j) es += expf(pv[j] - m);
    const float pt = tdot / ssum;
    const float ptc = fminf(fmaxf(pt, 1e-7f), 1.0f - 1e-7f);
    const float cp = -logf(ptc);
    const float cel = (m + logf(es)) - tdot;  // mining key (CE from logits)
    keys[idx] = isPos ? 0u : f2u(cel);
    cep[idx] = cp;
    pconf = isPos ? cp : 0.f;
    const float dx = p.x - a.x, dy = p.y - a.y, dz = p.z - a.z, dw = p.w - a.w;
    const float axv = fabsf(dx), ayv = fabsf(dy), azv = fabsf(dz), awv = fabsf(dw);
    const float h = (axv <= 1.f ? 0.5f * dx * dx : axv - 0.5f)
                  + (ayv <= 1.f ? 0.5f * dy * dy : ayv - 0.5f)
                  + (azv <= 1.f ? 0.5f * dz * dz : azv - 0.5f)
                  + (awv <= 1.f ? 0.5f * dw * dw : awv - 0.5f);
    loc = isPos ? h * 0.25f : 0.f;
  }
  // single-wave reduce + store per-block partials
  float lvv = loc, pcf = pconf;
  int pctr = isPos;
  for (int off = 32; off > 0; off >>= 1) {
    lvv += __shfl_down(lvv, off, 64);
    pcf += __shfl_down(pcf, off, 64);
    pctr += __shfl_down(pctr, off, 64);
  }
  if (tid == 0) {
    const int bi = b * GX + blockIdx.x;
    pl[bi] = lvv;
    pc[bi] = pcf;
    pcnt[bi] = pctr;
  }
}

// Kernel 2: per-row partial-reduce + exact radix-select (core unchanged
// since R2; GX-strided partial reduce).
#define K2T 1024
#define K2W 16

__global__ __launch_bounds__(K2T) void k2_select(
    const unsigned* __restrict__ keys, const float* __restrict__ cep,
    const float* __restrict__ pl, const float* __restrict__ pc,
    const int* __restrict__ pcnt,
    double* __restrict__ row_loc, double* __restrict__ row_conf,
    int* __restrict__ row_pos) {
  __shared__ unsigned hist[2048];
  __shared__ unsigned wsum[K2W];
  __shared__ unsigned bc[2];
  __shared__ unsigned wtot[K2W];
  __shared__ double s_d[K2W];
  __shared__ double s_rl, s_rc;
  __shared__ int s_pos;
  const int b = blockIdx.x;
  const int tid = threadIdx.x;
  const int lane = tid & 63, wv = tid >> 6;

  if (wv == 0) {
    float a = 0.f, c = 0.f;
    int p = 0;
    for (int i = lane; i < GX; i += 64) {
      a += pl[b * GX + i];
      c += pc[b * GX + i];
      p += pcnt[b * GX + i];
    }
    for (int off = 32; off > 0; off >>= 1) {
      a += __shfl_down(a, off, 64);
      c += __shfl_down(c, off, 64);
      p += __shfl_down(p, off, 64);
    }
    if (lane == 0) { s_rl = (double)a; s_rc = (double)c; s_pos = p; }
  }
  __syncthreads();
  const int pos = s_pos;
  unsigned k = (unsigned)(pos * 3);
  const unsigned negs = (unsigned)(NN - pos);
  if (k > negs) k = negs;

  double neg_total = 0.0;
  if (k > 0) {  // block-uniform branch
    const unsigned* rk = keys + (size_t)b * NN;
    const uint4* rk4 = reinterpret_cast<const uint4*>(rk);
    unsigned want = k;
    unsigned prefix = 0;
    for (int pass = 0; pass < 3; ++pass) {
      const int nb = (pass == 2) ? 1024 : 2048;
      const int shift = (pass == 0) ? 21 : (pass == 1) ? 10 : 0;
      for (int i = tid; i < nb; i += K2T) hist[i] = 0;
      __syncthreads();
      if (pass == 0) {
        for (int t = tid; t < NV4; t += K2T) {
          uint4 v = rk4[t];
          atomicAdd(&hist[v.x >> 21], 1u);
          atomicAdd(&hist[v.y >> 21], 1u);
          atomicAdd(&hist[v.z >> 21], 1u);
          atomicAdd(&hist[v.w >> 21], 1u);
        }
      } else {
        const unsigned pshift = (pass == 1) ? 21u : 10u;
        const unsigned msk = (unsigned)(nb - 1);
        for (int t = tid; t < NV4; t += K2T) {
          uint4 v = rk4[t];
          if ((v.x >> pshift) == prefix) atomicAdd(&hist[(v.x >> shift) & msk], 1u);
          if ((v.y >> pshift) == prefix) atomicAdd(&hist[(v.y >> shift) & msk], 1u);
          if ((v.z >> pshift) == prefix) atomicAdd(&hist[(v.z >> shift) & msk], 1u);
          if ((v.w >> pshift) == prefix) atomicAdd(&hist[(v.w >> shift) & msk], 1u);
        }
      }
      __syncthreads();
      const int PR = nb / K2T;
      unsigned v0, v1 = 0, ls;
      if (PR == 2) {
        v0 = hist[nb - 1 - (tid * 2)];
        v1 = hist[nb - 1 - (tid * 2 + 1)];
        ls = v0 + v1;
      } else {
        v0 = hist[nb - 1 - tid];
        ls = v0;
      }
      unsigned x = ls;
#pragma unroll
      for (int off = 1; off < 64; off <<= 1) {
        unsigned y = __shfl_up(x, off, 64);
        if (lane >= off) x += y;
      }
      if (lane == 63) wsum[wv] = x;
      __syncthreads();
      if (wv == 0 && lane < K2W) {
        unsigned wx = wsum[lane];
#pragma unroll
        for (int off = 1; off < K2W; off <<= 1) {
          unsigned wy = __shfl_up(wx, off, K2W);
          if ((lane & (K2W - 1)) >= off) wx += wy;
        }
        wsum[lane] = wx;
      }
      __syncthreads();
      const unsigned woff = (wv == 0) ? 0u : wsum[wv - 1];
      const unsigned pinc = woff + x;
      if (PR == 2) {
        const unsigned p0 = pinc - ls + v0;
        const unsigned p1 = pinc;
        if (v0 > 0 && p0 >= want && p0 - v0 < want) { bc[0] = (unsigned)(nb - 1 - tid * 2); bc[1] = want - (p0 - v0); }
        if (v1 > 0 && p1 >= want && p1 - v1 < want) { bc[0] = (unsigned)(nb - 1 - (tid * 2 + 1)); bc[1] = want - (p1 - v1); }
      } else {
        if (v0 > 0 && pinc >= want && pinc - v0 < want) { bc[0] = (unsigned)(nb - 1 - tid); bc[1] = want - (pinc - v0); }
      }
      __syncthreads();
      const unsigned d = bc[0];
      want = bc[1];
      prefix = (pass == 0) ? d : ((prefix << ((pass == 1) ? 11 : 10)) | d);
      __syncthreads();
    }
    const unsigned tau = prefix;
    const unsigned neq = want;

    const float* rc = cep + (size_t)b * NN;
    double mysum = 0.0;
    unsigned bbase = 0;
    for (int start = 0; start < NN; start += K2T) {
      const int i = start + tid;
      const unsigned key = (i < NN) ? rk[i] : 0u;
      const bool gt = (i < NN) && (key > tau);
      const bool eq = (i < NN) && (key == tau);
      if (gt) mysum += (double)rc[i];
      const unsigned long long mb = __ballot(eq);
      if (lane == 0) wtot[wv] = (unsigned)__popcll(mb);
      __syncthreads();
      unsigned wpref = 0, tot = 0;
#pragma unroll
      for (int w = 0; w < K2W; ++w) {
        const unsigned c = wtot[w];
        wpref += (w < wv) ? c : 0u;
        tot += c;
      }
      if (eq) {
        const unsigned lanepref = (unsigned)__popcll(mb & ((1ull << lane) - 1ull));
        if (bbase + wpref + lanepref < neq) mysum += (double)rc[i];
      }
      bbase += tot;
      __syncthreads();
    }
    for (int off = 32; off > 0; off >>= 1) mysum += __shfl_down(mysum, off, 64);
    if (lane == 0) s_d[wv] = mysum;
    __syncthreads();
    if (tid == 0) {
#pragma unroll
      for (int w = 0; w < K2W; ++w) neg_total += s_d[w];
    }
  }
  if (tid == 0) {
    row_loc[b] = s_rl;
    row_conf[b] = s_rc + neg_total;
    row_pos[b] = pos;
  }
}

// Kernel 3: reduce 64 rows, finalize the two scalars.
__global__ void k3_final(const double* __restrict__ row_loc,
                         const double* __restrict__ row_conf,
                         const int* __restrict__ row_pos,
                         float* __restrict__ out) {
  const int lane = threadIdx.x;  // 64 threads
  double l = row_loc[lane], c = row_conf[lane];
  int p = row_pos[lane];
  for (int off = 32; off > 0; off >>= 1) {
    l += __shfl_down(l, off, 64);
    c += __shfl_down(c, off, 64);
    p += __shfl_down(p, off, 64);
  }
  if (lane == 0) {
    const double tot = (p > 0) ? (double)p : 1.0;
    out[0] = (float)(l / tot);
    out[1] = (float)(c / tot);
  }
}

extern "C" void kernel_launch(void* const* d_in, const int* in_sizes, int n_in,
                              void* d_out, int out_size, void* d_ws, size_t ws_size,
                              hipStream_t stream) {
  const float* abd = (const float*)d_in[0];
  const float* lbl = (const float*)d_in[1];
  const float* pbd = (const float*)d_in[2];
  const float* plog = (const float*)d_in[3];

  char* ws = (char*)d_ws;
  float* pl = (float*)(ws + 0);               // [BB*GX] = 8768 (35072 B)
  float* pc = (float*)(ws + 36864);           // [8768]
  int* pcnt = (int*)(ws + 73728);             // [8768]
  double* row_loc = (double*)(ws + 110592);   // [64]
  double* row_conf = (double*)(ws + 111104);  // [64]
  int* row_pos = (int*)(ws + 111616);         // [64]
  unsigned* keys = (unsigned*)(ws + 112128);  // [B*N], 16B-aligned
  float* cep = (float*)(ws + 112128 + (size_t)BB * NN * sizeof(unsigned));

  // All scratch is written unconditionally before being read -> no memset.
  dim3 g1(GX, BB);
  k1_map<<<g1, TB, 0, stream>>>(abd, lbl, pbd, plog, keys, cep, pl, pc, pcnt);
  k2_select<<<BB, K2T, 0, stream>>>(keys, cep, pl, pc, pcnt, row_loc, row_conf, row_pos);
  k3_final<<<1, 64, 0, stream>>>(row_loc, row_conf, row_pos, (float*)d_out);
}